// Round 1
// baseline (566.332 us; speedup 1.0000x reference)
//
#include <hip/hip_runtime.h>

// Conv2D 7x7 VALID, fp32, 8192x8192 -> 8186x8186.
// Memory-bound (536 MB min traffic vs 42 us of fp32 VALU FLOPs).
// 64x64 output tile per 256-thread block; 70x70 input tile staged in LDS;
// each thread computes a 4x4 micro-tile with vector (b128) LDS reads.

#define IH 8192
#define IW 8192
#define OH 8186
#define OW 8186

#define TW 64            // output tile width
#define TH 64            // output tile height
#define IN_W 70          // TW + 6
#define IN_H 70          // TH + 6
#define LDS_STRIDE 76    // padded row stride (floats): multiple of 4, desyncs rows
#define QPR 18           // float4 loads per staged row (72 floats >= 70 needed)

__global__ __launch_bounds__(256)
void conv7x7_kernel(const float* __restrict__ x,
                    const float* __restrict__ wgt,
                    const float* __restrict__ bias,
                    float* __restrict__ out) {
    __shared__ float tile[IN_H * LDS_STRIDE];

    const int tid = threadIdx.x;
    const int C = blockIdx.x * TW;   // output col base == input col base (VALID)
    const int R = blockIdx.y * TH;   // output row base == input row base

    // ---- weights: uniform -> scalar loads -> SGPRs ----
    float w[49];
#pragma unroll
    for (int i = 0; i < 49; ++i) w[i] = wgt[i];
    const float b0 = bias[0];

    // ---- stage input tile (rows R..R+69, cols C..C+71) into LDS ----
    // 70 rows x 18 float4 = 1260 vec4 elements, grid-stride over 256 threads.
    for (int idx = tid; idx < IN_H * QPR; idx += 256) {
        const int row = idx / QPR;
        const int qc  = idx - row * QPR;
        const int gr  = R + row;
        const int gc  = C + qc * 4;
        float4 v;
        if (gr < IH && gc + 3 < IW) {
            v = *reinterpret_cast<const float4*>(&x[(size_t)gr * IW + gc]);
        } else {
            v.x = (gr < IH && gc + 0 < IW) ? x[(size_t)gr * IW + gc + 0] : 0.0f;
            v.y = (gr < IH && gc + 1 < IW) ? x[(size_t)gr * IW + gc + 1] : 0.0f;
            v.z = (gr < IH && gc + 2 < IW) ? x[(size_t)gr * IW + gc + 2] : 0.0f;
            v.w = (gr < IH && gc + 3 < IW) ? x[(size_t)gr * IW + gc + 3] : 0.0f;
        }
        *reinterpret_cast<float4*>(&tile[row * LDS_STRIDE + qc * 4]) = v;
    }
    __syncthreads();

    // ---- compute: thread (tx,ty) owns 4x4 outputs at (4*ty, 4*tx) ----
    const int tx = tid & 15;
    const int ty = tid >> 4;
    const int r0 = ty * 4;
    const int c0 = tx * 4;

    float acc[4][4];
#pragma unroll
    for (int o = 0; o < 4; ++o)
#pragma unroll
        for (int oc = 0; oc < 4; ++oc) acc[o][oc] = 0.0f;

#pragma unroll
    for (int ir = 0; ir < 10; ++ir) {
        // input row (r0+ir), cols c0..c0+11 : three b128 reads
        const float* lrow = &tile[(r0 + ir) * LDS_STRIDE + c0];
        const float4 fa = *reinterpret_cast<const float4*>(lrow + 0);
        const float4 fb = *reinterpret_cast<const float4*>(lrow + 4);
        const float4 fc = *reinterpret_cast<const float4*>(lrow + 8);
        float f[12];
        f[0] = fa.x; f[1] = fa.y; f[2]  = fa.z; f[3]  = fa.w;
        f[4] = fb.x; f[5] = fb.y; f[6]  = fb.z; f[7]  = fb.w;
        f[8] = fc.x; f[9] = fc.y; f[10] = fc.z; f[11] = fc.w;

#pragma unroll
        for (int o = 0; o < 4; ++o) {
            const int wr = ir - o;          // kernel row feeding output row o
            if (wr < 0 || wr > 6) continue; // compile-time after unroll
#pragma unroll
            for (int oc = 0; oc < 4; ++oc) {
#pragma unroll
                for (int j = 0; j < 7; ++j) {
                    acc[o][oc] += f[oc + j] * w[wr * 7 + j];
                }
            }
        }
    }

    // ---- store 4x4 micro-tile (float2: 8B-aligned; scalar at right edge) ----
    const int orow = R + r0;
    const int ocol = C + c0;
#pragma unroll
    for (int o = 0; o < 4; ++o) {
        const int gr = orow + o;
        if (gr >= OH) continue;
        float* orow_p = &out[(size_t)gr * OW + ocol];
        if (ocol + 3 < OW) {
            float2 s0 = make_float2(acc[o][0] + b0, acc[o][1] + b0);
            float2 s1 = make_float2(acc[o][2] + b0, acc[o][3] + b0);
            *reinterpret_cast<float2*>(orow_p + 0) = s0;
            *reinterpret_cast<float2*>(orow_p + 2) = s1;
        } else {
#pragma unroll
            for (int oc = 0; oc < 4; ++oc) {
                if (ocol + oc < OW) orow_p[oc] = acc[o][oc] + b0;
            }
        }
    }
}

extern "C" void kernel_launch(void* const* d_in, const int* in_sizes, int n_in,
                              void* d_out, int out_size, void* d_ws, size_t ws_size,
                              hipStream_t stream) {
    const float* x    = (const float*)d_in[0];
    const float* wgt  = (const float*)d_in[1];
    const float* bias = (const float*)d_in[2];
    float* out = (float*)d_out;

    dim3 grid((OW + TW - 1) / TW, (OH + TH - 1) / TH);  // 128 x 128
    conv7x7_kernel<<<grid, 256, 0, stream>>>(x, wgt, bias, out);
}